// Round 3
// baseline (33.425 us; speedup 1.0000x reference)
//
#include <hip/hip_runtime.h>

typedef float f32x2 __attribute__((ext_vector_type(2)));

#define NPTS 4096
#define BATCH 8
#define BLK 256
#define P 8                              // own points per thread (4 float2 pairs)
#define NPAIR (P / 2)                    // 4
#define CHUNK 256                        // staged points per block (4 KB LDS)
#define NCHUNK (NPTS / CHUNK)            // 16
#define OWN_PER_BLK (BLK * P)            // 2048
#define OWN_BLKS (NPTS / OWN_PER_BLK)    // 2 per batch
#define BLOCKS_PER_PASS (BATCH * OWN_BLKS * NCHUNK)  // 256
#define TOTAL_BLOCKS (2 * BLOCKS_PER_PASS)           // 512
#define HALF_OWN (BATCH * NPTS)          // 32768
#define TOTAL_OWN (2 * HALF_OWN)         // 65536
#define COMBINE_BLOCKS (TOTAL_OWN / BLK) // 256

static __device__ __forceinline__ f32x2 splat2(float v) {
    f32x2 r; r.x = v; r.y = v; return r;
}

// LDS entry: (-2x, -2y, -2z, ||q||^2). D = ||p||^2 + (||q||^2 - 2 p.q);
// ||p||^2 is thread-constant, added after the min.
__global__ __launch_bounds__(BLK) void chamfer_partial_kernel(
    const float* __restrict__ pred,   // [B,3,N]
    const float* __restrict__ gt,     // [B,M,3]
    float* __restrict__ partial)      // [NCHUNK][TOTAL_OWN]
{
    __shared__ float4 s[CHUNK];

    const int bid  = blockIdx.x;
    const int pass = bid / BLOCKS_PER_PASS;
    int r = bid - pass * BLOCKS_PER_PASS;
    const int c = r % NCHUNK;
    r /= NCHUNK;
    const int b = r / OWN_BLKS;
    const int j = r - b * OWN_BLKS;
    const int t = threadIdx.x;

    const float* p = pred + (size_t)b * 3 * NPTS;
    const float* g = gt   + (size_t)b * NPTS * 3;
    const int cbase = c * CHUNK;

    // Stage this block's chunk of the "other" set, prescaled (1 pt / thread).
    {
        int i = t;  // CHUNK == BLK
        if (pass == 0) {
            int gi = cbase + i;
            float gx = g[gi * 3 + 0], gy = g[gi * 3 + 1], gz = g[gi * 3 + 2];
            s[i] = make_float4(-2.f * gx, -2.f * gy, -2.f * gz,
                               fmaf(gx, gx, fmaf(gy, gy, gz * gz)));
        } else {
            int pi = cbase + i;
            float px = p[pi], py = p[NPTS + pi], pz = p[2 * NPTS + pi];
            s[i] = make_float4(-2.f * px, -2.f * py, -2.f * pz,
                               fmaf(px, px, fmaf(py, py, pz * pz)));
        }
    }

    // Own points: 8 per thread packed as 4 float2 lanes.
    f32x2 X[NPAIR], Y[NPAIR], Z[NPAIR], N2[NPAIR];
    #pragma unroll
    for (int k = 0; k < P; ++k) {
        int idx = j * OWN_PER_BLK + k * BLK + t;
        float x, y, z;
        if (pass == 0) {
            x = p[idx]; y = p[NPTS + idx]; z = p[2 * NPTS + idx];
        } else {
            x = g[idx * 3 + 0]; y = g[idx * 3 + 1]; z = g[idx * 3 + 2];
        }
        X[k >> 1][k & 1] = x;
        Y[k >> 1][k & 1] = y;
        Z[k >> 1][k & 1] = z;
        N2[k >> 1][k & 1] = fmaf(x, x, fmaf(y, y, z * z));
    }
    __syncthreads();

    // 2 packed min accumulators per own-pair -> 8 independent f32x2 chains.
    f32x2 A[NPAIR], B[NPAIR];
    #pragma unroll
    for (int pk = 0; pk < NPAIR; ++pk) { A[pk] = splat2(3.4e38f); B[pk] = splat2(3.4e38f); }

    #pragma unroll 2
    for (int mm = 0; mm < CHUNK; mm += 2) {
        float4 q0 = s[mm + 0];
        float4 q1 = s[mm + 1];
        f32x2 q0x = splat2(q0.x), q0y = splat2(q0.y), q0z = splat2(q0.z), q0w = splat2(q0.w);
        f32x2 q1x = splat2(q1.x), q1y = splat2(q1.y), q1z = splat2(q1.z), q1w = splat2(q1.w);
        #pragma unroll
        for (int pk = 0; pk < NPAIR; ++pk) {
            f32x2 d0 = __builtin_elementwise_fma(X[pk], q0x,
                        __builtin_elementwise_fma(Y[pk], q0y,
                         __builtin_elementwise_fma(Z[pk], q0z, q0w)));
            A[pk] = __builtin_elementwise_min(A[pk], d0);
            f32x2 d1 = __builtin_elementwise_fma(X[pk], q1x,
                        __builtin_elementwise_fma(Y[pk], q1y,
                         __builtin_elementwise_fma(Z[pk], q1z, q1w)));
            B[pk] = __builtin_elementwise_min(B[pk], d1);
        }
    }

    #pragma unroll
    for (int pk = 0; pk < NPAIR; ++pk) {
        f32x2 mn = __builtin_elementwise_min(A[pk], B[pk]);
        #pragma unroll
        for (int h = 0; h < 2; ++h) {
            int k = 2 * pk + h;
            int idx = j * OWN_PER_BLK + k * BLK + t;
            int o = pass * HALF_OWN + b * NPTS + idx;
            partial[(size_t)c * TOTAL_OWN + o] = N2[pk][h] + mn[h];
        }
    }
}

// Min over chunks per own point, then block partial sums.
__global__ __launch_bounds__(BLK) void chamfer_combine_kernel(
    const float* __restrict__ partial, float* __restrict__ bsum)
{
    __shared__ float red[BLK / 64];
    const int t = threadIdx.x;
    const int o = blockIdx.x * BLK + t;
    float v = 3.4e38f;
    #pragma unroll
    for (int c = 0; c < NCHUNK; ++c)
        v = fminf(v, partial[(size_t)c * TOTAL_OWN + o]);
    #pragma unroll
    for (int off = 32; off > 0; off >>= 1)
        v += __shfl_down(v, off, 64);
    if ((t & 63) == 0) red[t >> 6] = v;
    __syncthreads();
    if (t == 0) bsum[blockIdx.x] = red[0] + red[1] + red[2] + red[3];
}

__global__ __launch_bounds__(COMBINE_BLOCKS) void chamfer_final_kernel(
    const float* __restrict__ bsum, float* __restrict__ out)
{
    __shared__ float red[COMBINE_BLOCKS / 64];
    const int t = threadIdx.x;
    float v = bsum[t];
    #pragma unroll
    for (int off = 32; off > 0; off >>= 1)
        v += __shfl_down(v, off, 64);
    if ((t & 63) == 0) red[t >> 6] = v;
    __syncthreads();
    if (t == 0) {
        float s = 0.f;
        #pragma unroll
        for (int w = 0; w < COMBINE_BLOCKS / 64; ++w) s += red[w];
        // loss = (sum of all mins) / (NPTS * BATCH)   (N == M)
        out[0] = s * (1.0f / ((float)NPTS * (float)BATCH));
    }
}

extern "C" void kernel_launch(void* const* d_in, const int* in_sizes, int n_in,
                              void* d_out, int out_size, void* d_ws, size_t ws_size,
                              hipStream_t stream) {
    const float* pred = (const float*)d_in[0];  // [8,3,4096]
    const float* gt   = (const float*)d_in[1];  // [8,4096,3]
    float* out = (float*)d_out;

    float* partial = (float*)d_ws;                                  // 16*65536 floats = 4 MB
    float* bsum    = partial + (size_t)NCHUNK * TOTAL_OWN;          // 256 floats

    chamfer_partial_kernel<<<TOTAL_BLOCKS, BLK, 0, stream>>>(pred, gt, partial);
    chamfer_combine_kernel<<<COMBINE_BLOCKS, BLK, 0, stream>>>(partial, bsum);
    chamfer_final_kernel<<<1, COMBINE_BLOCKS, 0, stream>>>(bsum, out);
}